// Round 1
// baseline (1171.240 us; speedup 1.0000x reference)
//
#include <hip/hip_runtime.h>

// BPR loss with negative sampling, B=64, T=200, V=20000, S=1.
// loss = sum_b [ -(1/L_b^2) * sum_{i<L,j<L} log_sigmoid(out[b,i,lab[b,j]] - out[b,i,neg[b,j]]) ]
//
// R2: per-block partials in d_ws + one-block tree reduce (removed serialized atomics).
// R3: the partial kernel was a latency-bound random HBM gather (~0.44 TB/s effective,
//     1 wave/block, dependent index->gather chains). Restructure: one 1024-thread
//     block per (b,i) stages the full 80 KB row into LDS with coalesced float4
//     streaming (2 blocks/CU, 32 waves/CU), then the <=200 pair gathers hit LDS.
//     HBM traffic becomes ~515 MB sequential at ~6 TB/s instead of ~200 MB of
//     line-granular random access at ~0.4 TB/s.

#define BB 64
#define TT 200
#define VV 20000
#define NBLK (BB * TT)
#define NT 1024

__global__ __launch_bounds__(NT) void bpr_partial_kernel(
    const float* __restrict__ output,
    const int*   __restrict__ labels,
    const int*   __restrict__ x_lens,
    const int*   __restrict__ neg_ids,
    float*       __restrict__ partial)
{
    __shared__ float row_s[VV];        // 80,000 B — 2 workgroups/CU on 160 KiB LDS
    __shared__ float wsum[NT / 64];

    const int blk = blockIdx.x;
    const int b   = blk / TT;
    const int i   = blk - b * TT;
    const int L   = x_lens[b];
    const int tid = threadIdx.x;

    float sum = 0.0f;
    if (i < L) {                       // uniform per block — safe around barriers
        // Stage the whole row coalesced: 5000 float4 over 1024 threads (5 iters).
        const float4* __restrict__ src =
            reinterpret_cast<const float4*>(output + ((size_t)b * TT + i) * VV);
        float4* dst = reinterpret_cast<float4*>(row_s);
        #pragma unroll
        for (int k = 0; k < 5; ++k) {
            const int idx = tid + k * NT;
            if (idx < VV / 4) dst[idx] = src[idx];
        }
        __syncthreads();

        // L <= 200 < 1024: one pair per thread, no loop, all gathers from LDS.
        if (tid < L) {
            const int* __restrict__ lab = labels  + b * TT;
            const int* __restrict__ neg = neg_ids + b * TT;
            const float xp = row_s[lab[tid]];
            const float xn = row_s[neg[tid]];
            const float d  = xp - xn;
            // stable log_sigmoid(d) = min(d,0) - log1p(exp(-|d|))
            sum = fminf(d, 0.0f) - log1pf(__expf(-fabsf(d)));
        }
    }

    // Block reduction: wave64 butterfly, then first wave folds the 16 wave sums.
    #pragma unroll
    for (int off = 32; off > 0; off >>= 1)
        sum += __shfl_down(sum, off, 64);
    if ((tid & 63) == 0) wsum[tid >> 6] = sum;
    __syncthreads();

    if (tid < 64) {
        float v = (tid < 16) ? wsum[tid] : 0.0f;
        #pragma unroll
        for (int off = 32; off > 0; off >>= 1)
            v += __shfl_down(v, off, 64);
        if (tid == 0) {
            const float Lf = (float)L;         // L >= 1 always
            partial[blk] = -v / (Lf * Lf);     // 0 when i >= L (ws poisoned -> must write)
        }
    }
}

__global__ __launch_bounds__(1024) void bpr_reduce_kernel(
    const float* __restrict__ partial, float* __restrict__ out)
{
    float s = 0.0f;
    for (int k = threadIdx.x; k < NBLK; k += 1024)
        s += partial[k];

    __shared__ float wsum[16];
    #pragma unroll
    for (int off = 32; off > 0; off >>= 1)
        s += __shfl_down(s, off, 64);
    if ((threadIdx.x & 63) == 0) wsum[threadIdx.x >> 6] = s;
    __syncthreads();

    if (threadIdx.x < 64) {
        float v = (threadIdx.x < 16) ? wsum[threadIdx.x] : 0.0f;
        #pragma unroll
        for (int off = 32; off > 0; off >>= 1)
            v += __shfl_down(v, off, 64);
        if (threadIdx.x == 0) out[0] = v;
    }
}

extern "C" void kernel_launch(void* const* d_in, const int* in_sizes, int n_in,
                              void* d_out, int out_size, void* d_ws, size_t ws_size,
                              hipStream_t stream) {
    const float* output  = (const float*)d_in[0];
    const int*   labels  = (const int*)d_in[1];
    const int*   x_lens  = (const int*)d_in[2];
    // d_in[3] = uids (unused by the reference computation)
    const int*   neg_ids = (const int*)d_in[4];
    float* partial = (float*)d_ws;          // NBLK floats = 51.2 KB
    float* result  = (float*)d_out;

    bpr_partial_kernel<<<NBLK, NT, 0, stream>>>(output, labels, x_lens, neg_ids, partial);
    bpr_reduce_kernel<<<1, 1024, 0, stream>>>(partial, result);
}